// Round 11
// baseline (152.489 us; speedup 1.0000x reference)
//
#include <hip/hip_runtime.h>

#define N_NODES 100000
#define N_EDGES 800000
#define NBY    ((N_NODES + 255) / 256)             // 391
#define YBLK   (NBY * 4)                           // 1564 y-blocks
#define HBLK   ((N_EDGES + 255) / 256)             // 3125
#define OVF_CAP 65536
#define GA     500                                 // phase-A bucket blocks
#define CHUNK  1600                                // edges per phase-A block (500*1600 = 800000)
                                                   // NOTE: CHUNK % 256 != 0 -> every chunk-loop
                                                   // needs the (i + tid < CHUNK) guard! (R10 bug)
#define NBINS  512
#define NPB    196                                 // nodes per bin (512*196 = 100352)
#define CAPB   2048                                // slots/bin (mean 1562, sigma ~40)
#define GB_T   1024                                // gather block threads
// Y layout: [n][kx][ky][o] bf16 (ushort), plane = 256 ushort = 512 B per node

__device__ __forceinline__ unsigned short f2bf(float f) {
    union { float f; unsigned u; } v; v.f = f;
    unsigned u = v.u;
    return (unsigned short)((u + 0x7FFFu + ((u >> 16) & 1u)) >> 16);  // RNE
}
__device__ __forceinline__ float bflo(unsigned u) {
    union { unsigned u; float f; } v; v.u = u << 16; return v.f;
}
__device__ __forceinline__ float bfhi(unsigned u) {
    union { unsigned u; float f; } v; v.u = u & 0xFFFF0000u; return v.f;
}

// ---- fused: phase-A bucket build [0,GA) | y-transform [GA, GA+YBLK) ----
__global__ __launch_bounds__(256) void fused_bucket_y(
    const float* __restrict__ x, const float* __restrict__ W,
    unsigned short* __restrict__ Y, const float* __restrict__ edge_attr,
    const int* __restrict__ ei, const int* __restrict__ ej,
    int* __restrict__ cursor, uint2* __restrict__ bkt,
    int* __restrict__ ovfCnt, int* __restrict__ ovf) {
    const int b = blockIdx.x;
    if (b < GA) {
        __shared__ int hist[NBINS];
        const int tid = threadIdx.x;
        for (int k = tid; k < NBINS; k += 256) hist[k] = 0;
        __syncthreads();
        const int base = b * CHUNK;

        // pass 1: LDS histogram over bins (6.25 iters; guard against chunk end)
        for (int i = 0; i < CHUNK; i += 256) {
            const int j = i + tid;
            const int e = base + j;
            if (j < CHUNK && e < N_EDGES) {
                const int di = ei[e];
                if (di != ej[e]) atomicAdd(&hist[di / NPB], 1);
            }
        }
        __syncthreads();

        // pass 2: one returning global atomic per non-empty (block,bin)
        for (int k = tid; k < NBINS; k += 256) {
            const int c = hist[k];
            int g = 0;
            if (c > 0) g = atomicAdd(&cursor[k], c);
            hist[k] = k * CAPB + g;
        }
        __syncthreads();

        // pass 3: re-scan, slot via LDS returning atomic, write 8B record
        for (int i = 0; i < CHUNK; i += 256) {
            const int j = i + tid;
            const int e = base + j;
            if (j >= CHUNK || e >= N_EDGES) continue;   // chunk-boundary guard (R10 bug fix)
            const int di = ei[e];
            const int sj = ej[e];
            if (di == sj) continue;                     // centerIgnore
            const float2 ea = ((const float2*)edge_attr)[e];
            float ux = fminf(fmaxf(ea.x, -1.f), 1.f);
            float uy = fminf(fmaxf(ea.y, -1.f), 1.f);
            float tx = (ux + 1.f) * 1.5f;
            float ty = (uy + 1.f) * 1.5f;
            int kx0 = min((int)tx, 2);
            int ky0 = min((int)ty, 2);
            float fx = tx - (float)kx0;
            float fy = ty - (float)ky0;
            unsigned fx12 = (unsigned)(fx * 4095.f + 0.5f);
            unsigned fy12 = (unsigned)(fy * 4095.f + 0.5f);
            const int bin = di / NPB;
            const unsigned local = (unsigned)(di - bin * NPB);   // < 196, 8 bits

            const int s = atomicAdd(&hist[bin], 1);
            if (s - bin * CAPB < CAPB) {
                bkt[s] = make_uint2((unsigned)(sj * 512 + (kx0 * 4 + ky0) * 32),
                                    fx12 | (fy12 << 12) | (local << 24));
            } else {
                const int o = atomicAdd(ovfCnt, 1);
                if (o < OVF_CAP) ovf[o] = e;
            }
        }
    } else {
        const int bb = b - GA;
        const int kbase = (bb / NBY) * 4;
        const int n = (bb % NBY) * 256 + threadIdx.x;
        if (n >= N_NODES) return;

        const float4* xv = (const float4*)(x + n * 16);
        float4 a = xv[0], b2 = xv[1], c = xv[2], d = xv[3];
        float xr[16] = {a.x,a.y,a.z,a.w, b2.x,b2.y,b2.z,b2.w,
                        c.x,c.y,c.z,c.w, d.x,d.y,d.z,d.w};

        float acc[4][16];
#pragma unroll
        for (int kk = 0; kk < 4; ++kk)
#pragma unroll
            for (int o = 0; o < 16; ++o) acc[kk][o] = 0.f;

#pragma unroll
        for (int i = 0; i < 16; ++i) {
#pragma unroll
            for (int kk = 0; kk < 4; ++kk) {
                const float* wrow = W + ((kbase + kk) * 256 + i * 16);
#pragma unroll
                for (int o = 0; o < 16; ++o)
                    acc[kk][o] = fmaf(xr[i], wrow[o], acc[kk][o]);
            }
        }

        unsigned short* dst = Y + (size_t)n * 256 + kbase * 16;
#pragma unroll
        for (int kk = 0; kk < 4; ++kk) {
            unsigned pk[8];
#pragma unroll
            for (int q = 0; q < 8; ++q)
                pk[q] = (unsigned)f2bf(acc[kk][2*q]) | ((unsigned)f2bf(acc[kk][2*q+1]) << 16);
            uint4* p = (uint4*)(dst + kk * 16);
            p[0] = make_uint4(pk[0], pk[1], pk[2], pk[3]);
            p[1] = make_uint4(pk[4], pk[5], pk[6], pk[7]);
        }
    }
}

// ---- gather: one block per bin; LDS counting-sort; 4 threads/node register acc ----
__global__ __launch_bounds__(GB_T) void gather_sort(
    const int* __restrict__ cursor, const uint2* __restrict__ bkt,
    const unsigned short* __restrict__ Y, float* __restrict__ out) {
    const int bin = blockIdx.x;
    const int tid = threadIdx.x;
    __shared__ uint2 sorted[CAPB];        // 16 KB
    __shared__ int h[NPB];                // counts -> inclusive scan
    __shared__ int st[NPB], en[NPB], cur[NPB];
    __shared__ float tile[NPB * 16];      // 12.5 KB

    for (int j = tid; j < NPB; j += GB_T) h[j] = 0;
    __syncthreads();

    const int cnt = min(cursor[bin], CAPB);
    const uint2* rb = bkt + (size_t)bin * CAPB;

    // stage 1: histogram over local nodes (~2 iters)
    for (int p = tid; p < cnt; p += GB_T)
        atomicAdd(&h[rb[p].y >> 24], 1);
    __syncthreads();

    // stage 2: Hillis-Steele inclusive scan of h[0..NPB)
    int c0 = (tid < NPB) ? h[tid] : 0;
    for (int off = 1; off < NPB; off <<= 1) {
        int tmp = 0;
        if (tid < NPB && tid >= off) tmp = h[tid - off];
        __syncthreads();
        if (tid < NPB) h[tid] += tmp;
        __syncthreads();
    }
    if (tid < NPB) {
        en[tid]  = h[tid];
        st[tid]  = h[tid] - c0;
        cur[tid] = h[tid] - c0;
    }
    __syncthreads();

    // stage 3: scatter records into sorted order (2nd read is L2-hot)
    for (int p = tid; p < cnt; p += GB_T) {
        uint2 r = rb[p];
        int pos = atomicAdd(&cur[r.y >> 24], 1);
        sorted[pos] = r;
    }
    __syncthreads();

    // stage 4: 4 threads per node (784 active), register accumulation
    const char* Yb = (const char*)Y;
    const float U = 1.f / 4095.f;
    const float S = 1.f / 128.f;                 // OUTPUT_SCALING
    if (tid < 4 * NPB) {
        const int node = tid >> 2;
        const int q4 = tid & 3;
        float acc[16];
#pragma unroll
        for (int o = 0; o < 16; ++o) acc[o] = 0.f;

        const int lo = st[node], hi2 = en[node];
        for (int idx = lo + q4; idx < hi2; idx += 4) {
            const uint2 m = sorted[idx];
            const float fx = (float)(m.y & 0xFFFu) * U;
            const float fy = (float)((m.y >> 12) & 0xFFFu) * U;
            const float w00 = (1.f - fx) * (1.f - fy) * S;
            const float w01 = (1.f - fx) * fy * S;
            const float w10 = fx * (1.f - fy) * S;
            const float w11 = fx * fy * S;

            const uint4* pA = (const uint4*)(Yb + m.x);
            const uint4* pB = (const uint4*)(Yb + m.x + 128);
            uint4 a0 = pA[0], a1 = pA[1], a2 = pA[2], a3 = pA[3];
            uint4 b0 = pB[0], b1 = pB[1], b2 = pB[2], b3 = pB[3];

            unsigned ra0[8] = {a0.x,a0.y,a0.z,a0.w, a1.x,a1.y,a1.z,a1.w};
            unsigned ra1[8] = {a2.x,a2.y,a2.z,a2.w, a3.x,a3.y,a3.z,a3.w};
            unsigned rb0[8] = {b0.x,b0.y,b0.z,b0.w, b1.x,b1.y,b1.z,b1.w};
            unsigned rb1[8] = {b2.x,b2.y,b2.z,b2.w, b3.x,b3.y,b3.z,b3.w};

#pragma unroll
            for (int q = 0; q < 8; ++q) {
                acc[2*q]   += bflo(ra0[q]) * w00 + bflo(ra1[q]) * w01
                            + bflo(rb0[q]) * w10 + bflo(rb1[q]) * w11;
                acc[2*q+1] += bfhi(ra0[q]) * w00 + bfhi(ra1[q]) * w01
                            + bfhi(rb0[q]) * w10 + bfhi(rb1[q]) * w11;
            }
        }
        // reduce across the 4-lane group (groups are lane-aligned, all active)
#pragma unroll
        for (int o = 0; o < 16; ++o) {
            acc[o] += __shfl_xor(acc[o], 1);
            acc[o] += __shfl_xor(acc[o], 2);
        }
        if (q4 == 0) {
            float* tr = &tile[node * 16];
#pragma unroll
            for (int o = 0; o < 16; ++o) tr[o] = acc[o];
        }
    }
    __syncthreads();

    // stage 5: coalesced block store (bins own disjoint node ranges)
    const int base = bin * NPB * 16;
    const int lim = N_NODES * 16 - base;
    for (int j = tid; j < NPB * 16; j += GB_T)
        if (j < lim) out[base + j] = tile[j];
}

// overflow fix-up: direct-compute rare capacity-overflow edges, atomic add.
__global__ __launch_bounds__(256) void overflow_kernel(
    const int* __restrict__ ovfCnt, const int* __restrict__ ovf,
    const float* __restrict__ x, const float* __restrict__ edge_attr,
    const float* __restrict__ W, const int* __restrict__ ei,
    const int* __restrict__ ej, float* __restrict__ out) {
    const int m = min(*ovfCnt, OVF_CAP);
    for (int i = blockIdx.x * 256 + threadIdx.x; i < m; i += gridDim.x * 256) {
        const int e = ovf[i];
        const int di = ei[e];
        const int sj = ej[e];
        const float2 ea = ((const float2*)edge_attr)[e];
        float ux = fminf(fmaxf(ea.x, -1.f), 1.f);
        float uy = fminf(fmaxf(ea.y, -1.f), 1.f);
        float tx = (ux + 1.f) * 1.5f, ty = (uy + 1.f) * 1.5f;
        int kx0 = min((int)tx, 2), ky0 = min((int)ty, 2);
        float fx = tx - (float)kx0, fy = ty - (float)ky0;
        const float S = 1.f / 128.f;
        float wgt[4] = {(1.f-fx)*(1.f-fy)*S, (1.f-fx)*fy*S, fx*(1.f-fy)*S, fx*fy*S};
        int kidx[4] = {kx0*4+ky0, kx0*4+ky0+1, (kx0+1)*4+ky0, (kx0+1)*4+ky0+1};

        const float* xj = x + (size_t)sj * 16;
        float msg[16];
#pragma unroll
        for (int o = 0; o < 16; ++o) msg[o] = 0.f;
#pragma unroll
        for (int p = 0; p < 4; ++p) {
            const float* wk = W + kidx[p] * 256;
            for (int ii = 0; ii < 16; ++ii) {
                float xw = xj[ii] * wgt[p];
#pragma unroll
                for (int o = 0; o < 16; ++o)
                    msg[o] = fmaf(xw, wk[ii * 16 + o], msg[o]);
            }
        }
        float* o16 = out + (size_t)di * 16;
#pragma unroll
        for (int o = 0; o < 16; ++o) atomicAdd(o16 + o, msg[o]);
    }
}

// ================= fallbacks =================
__global__ __launch_bounds__(256) void y_only_kernel(
    const float* __restrict__ x, const float* __restrict__ W,
    unsigned short* __restrict__ Y) {
    const int n = blockIdx.x * 256 + threadIdx.x;
    const int kbase = blockIdx.y * 4;
    if (n >= N_NODES) return;
    const float4* xv = (const float4*)(x + n * 16);
    float4 a = xv[0], b = xv[1], c = xv[2], d = xv[3];
    float xr[16] = {a.x,a.y,a.z,a.w, b.x,b.y,b.z,b.w,
                    c.x,c.y,c.z,c.w, d.x,d.y,d.z,d.w};
    float acc[4][16];
#pragma unroll
    for (int kk = 0; kk < 4; ++kk)
#pragma unroll
        for (int o = 0; o < 16; ++o) acc[kk][o] = 0.f;
#pragma unroll
    for (int i = 0; i < 16; ++i)
#pragma unroll
        for (int kk = 0; kk < 4; ++kk) {
            const float* wrow = W + ((kbase + kk) * 256 + i * 16);
#pragma unroll
            for (int o = 0; o < 16; ++o)
                acc[kk][o] = fmaf(xr[i], wrow[o], acc[kk][o]);
        }
    unsigned short* dst = Y + (size_t)n * 256 + kbase * 16;
#pragma unroll
    for (int kk = 0; kk < 4; ++kk) {
        unsigned pk[8];
#pragma unroll
        for (int q = 0; q < 8; ++q)
            pk[q] = (unsigned)f2bf(acc[kk][2*q]) | ((unsigned)f2bf(acc[kk][2*q+1]) << 16);
        uint4* p = (uint4*)(dst + kk * 16);
        p[0] = make_uint4(pk[0], pk[1], pk[2], pk[3]);
        p[1] = make_uint4(pk[4], pk[5], pk[6], pk[7]);
    }
}

__global__ __launch_bounds__(256) void edge_kernel(
    const float* __restrict__ edge_attr, const int* __restrict__ ei,
    const int* __restrict__ ej, const unsigned short* __restrict__ Y,
    float* __restrict__ out) {
    const int e = blockIdx.x * 256 + threadIdx.x;
    if (e >= N_EDGES) return;
    const int di = ei[e];
    const int sj = ej[e];
    const float2 ea = ((const float2*)edge_attr)[e];
    if (di == sj) return;
    float ux = fminf(fmaxf(ea.x, -1.f), 1.f);
    float uy = fminf(fmaxf(ea.y, -1.f), 1.f);
    float tx = (ux + 1.f) * 1.5f;
    float ty = (uy + 1.f) * 1.5f;
    int kx0 = min((int)tx, 2);
    int ky0 = min((int)ty, 2);
    float fx = tx - (float)kx0;
    float fy = ty - (float)ky0;
    const float S = 1.f / 128.f;
    float w00 = (1.f - fx) * (1.f - fy) * S;
    float w01 = (1.f - fx) * fy * S;
    float w10 = fx * (1.f - fy) * S;
    float w11 = fx * fy * S;
    const unsigned short* base = Y + (size_t)sj * 256 + (kx0 * 4 + ky0) * 16;
    const uint4* pA = (const uint4*)base;
    const uint4* pB = (const uint4*)(base + 64);
    uint4 a0 = pA[0], a1 = pA[1], a2 = pA[2], a3 = pA[3];
    uint4 b0 = pB[0], b1 = pB[1], b2 = pB[2], b3 = pB[3];
    unsigned ra0[8] = {a0.x,a0.y,a0.z,a0.w, a1.x,a1.y,a1.z,a1.w};
    unsigned ra1[8] = {a2.x,a2.y,a2.z,a2.w, a3.x,a3.y,a3.z,a3.w};
    unsigned rb0[8] = {b0.x,b0.y,b0.z,b0.w, b1.x,b1.y,b1.z,b1.w};
    unsigned rb1[8] = {b2.x,b2.y,b2.z,b2.w, b3.x,b3.y,b3.z,b3.w};
    float* o16 = out + (size_t)di * 16;
#pragma unroll
    for (int q = 0; q < 8; ++q) {
        float m0 = bflo(ra0[q]) * w00 + bflo(ra1[q]) * w01
                 + bflo(rb0[q]) * w10 + bflo(rb1[q]) * w11;
        float m1 = bfhi(ra0[q]) * w00 + bfhi(ra1[q]) * w01
                 + bfhi(rb0[q]) * w10 + bfhi(rb1[q]) * w11;
        atomicAdd(o16 + 2 * q, m0);
        atomicAdd(o16 + 2 * q + 1, m1);
    }
}

__global__ __launch_bounds__(256) void edge_direct(
    const float* __restrict__ x, const float* __restrict__ edge_attr,
    const float* __restrict__ W, const int* __restrict__ ei,
    const int* __restrict__ ej, float* __restrict__ out) {
    const int e = blockIdx.x * 256 + threadIdx.x;
    if (e >= N_EDGES) return;
    const int di = ei[e];
    const int sj = ej[e];
    const float2 ea = ((const float2*)edge_attr)[e];
    if (di == sj) return;
    float ux = fminf(fmaxf(ea.x, -1.f), 1.f);
    float uy = fminf(fmaxf(ea.y, -1.f), 1.f);
    float tx = (ux + 1.f) * 1.5f, ty = (uy + 1.f) * 1.5f;
    int kx0 = min((int)tx, 2), ky0 = min((int)ty, 2);
    float fx = tx - (float)kx0, fy = ty - (float)ky0;
    const float S = 1.f / 128.f;
    float wgt[4] = {(1.f-fx)*(1.f-fy)*S, (1.f-fx)*fy*S, fx*(1.f-fy)*S, fx*fy*S};
    int kidx[4] = {kx0*4+ky0, kx0*4+ky0+1, (kx0+1)*4+ky0, (kx0+1)*4+ky0+1};
    const float* xj = x + (size_t)sj * 16;
    float xr[16];
#pragma unroll
    for (int i = 0; i < 16; ++i) xr[i] = xj[i];
    float msg[16];
#pragma unroll
    for (int o = 0; o < 16; ++o) msg[o] = 0.f;
#pragma unroll
    for (int p = 0; p < 4; ++p) {
        const float* wk = W + kidx[p] * 256;
#pragma unroll
        for (int i = 0; i < 16; ++i) {
            float xw = xr[i] * wgt[p];
#pragma unroll
            for (int o = 0; o < 16; ++o)
                msg[o] = fmaf(xw, wk[i * 16 + o], msg[o]);
        }
    }
    float* o16 = out + (size_t)di * 16;
#pragma unroll
    for (int o = 0; o < 16; ++o) atomicAdd(o16 + o, msg[o]);
}

extern "C" void kernel_launch(void* const* d_in, const int* in_sizes, int n_in,
                              void* d_out, int out_size, void* d_ws, size_t ws_size,
                              hipStream_t stream) {
    const float* x         = (const float*)d_in[0];
    const float* edge_attr = (const float*)d_in[1];
    const float* W         = (const float*)d_in[2];
    const int*   ei        = (const int*)d_in[3];
    const int*   ej        = (const int*)d_in[4];
    float* out = (float*)d_out;
    char* ws = (char*)d_ws;

    // ---- bin-path workspace layout (16B aligned) ----
    const size_t oY      = 0;                                // 51,200,000
    const size_t oCur    = oY + (size_t)N_NODES * 512;       // 2,048
    const size_t oOvfCnt = oCur + (size_t)NBINS * 4;         // 16
    const size_t oOvf    = oOvfCnt + 16;                     // 262,144
    const size_t oBkt    = oOvf + (size_t)OVF_CAP * 4;       // NBINS*CAPB*8 = 8,388,608
    const size_t total   = oBkt + (size_t)NBINS * CAPB * 8;  // ~60 MB

    if (ws_size >= total) {
        unsigned short* Y = (unsigned short*)(ws + oY);
        int*   cursor = (int*)(ws + oCur);
        int*   ovfCnt = (int*)(ws + oOvfCnt);
        int*   ovf    = (int*)(ws + oOvf);
        uint2* bkt    = (uint2*)(ws + oBkt);

        hipMemsetAsync(cursor, 0, (size_t)NBINS * 4 + 16, stream);  // cursors + ovfCnt
        fused_bucket_y<<<GA + YBLK, 256, 0, stream>>>(
            x, W, Y, edge_attr, ei, ej, cursor, bkt, ovfCnt, ovf);
        gather_sort<<<NBINS, GB_T, 0, stream>>>(cursor, bkt, Y, out);
        overflow_kernel<<<32, 256, 0, stream>>>(ovfCnt, ovf, x, edge_attr, W, ei, ej, out);
        return;
    }

    const size_t yBytes = (size_t)N_NODES * 512;
    if (ws_size >= yBytes) {
        hipMemsetAsync(d_out, 0, (size_t)out_size * sizeof(float), stream);
        unsigned short* Y = (unsigned short*)d_ws;
        dim3 gA(NBY, 4);
        y_only_kernel<<<gA, 256, 0, stream>>>(x, W, Y);
        edge_kernel<<<HBLK, 256, 0, stream>>>(edge_attr, ei, ej, Y, out);
    } else {
        hipMemsetAsync(d_out, 0, (size_t)out_size * sizeof(float), stream);
        edge_direct<<<HBLK, 256, 0, stream>>>(x, edge_attr, W, ei, ej, out);
    }
}

// Round 12
// 151.282 us; speedup vs baseline: 1.0080x; 1.0080x over previous
//
#include <hip/hip_runtime.h>

#define N_NODES 100000
#define N_EDGES 800000
#define NBY    ((N_NODES + 255) / 256)             // 391
#define YBLK   (NBY * 4)                           // 1564 y-blocks
#define HBLK   ((N_EDGES + 255) / 256)             // 3125
#define OVF_CAP 65536
#define GA     500                                 // phase-A bucket blocks
#define CHUNK  1600                                // edges per phase-A block (500*1600 = 800000)
                                                   // CHUNK % 256 != 0 -> chunk loops need j<CHUNK guard
#define NBINS  512
#define NPB    196                                 // nodes per bin (512*196 = 100352)
#define CAPB   2048                                // slots/bin (mean 1562, sigma ~40)
#define GB_T   1024                                // gather block threads
// Y layout: [n][kx][ky][o] bf16 (ushort), plane = 256 ushort = 512 B per node

__device__ __forceinline__ unsigned short f2bf(float f) {
    union { float f; unsigned u; } v; v.f = f;
    unsigned u = v.u;
    return (unsigned short)((u + 0x7FFFu + ((u >> 16) & 1u)) >> 16);  // RNE
}
__device__ __forceinline__ float bflo(unsigned u) {
    union { unsigned u; float f; } v; v.u = u << 16; return v.f;
}
__device__ __forceinline__ float bfhi(unsigned u) {
    union { unsigned u; float f; } v; v.u = u & 0xFFFF0000u; return v.f;
}

// ---- fused: phase-A bucket build [0,GA) | y-transform [GA, GA+YBLK) ----
// Edge blocks: pass 1 reads edges ONCE, computes records into LDS + histogram;
// pass 2 allocates global runs (one returning atomic per (block,bin));
// pass 3 replays from LDS: slot via LDS atomic, 8B global store.
__global__ __launch_bounds__(256) void fused_bucket_y(
    const float* __restrict__ x, const float* __restrict__ W,
    unsigned short* __restrict__ Y, const float* __restrict__ edge_attr,
    const int* __restrict__ ei, const int* __restrict__ ej,
    int* __restrict__ cursor, uint2* __restrict__ bkt,
    int* __restrict__ ovfCnt, int* __restrict__ ovf) {
    const int b = blockIdx.x;
    if (b < GA) {
        __shared__ int hist[NBINS];            // 2 KB
        __shared__ unsigned rawA[CHUNK];       // 6.4 KB
        __shared__ unsigned rawB[CHUNK];       // 6.4 KB
        __shared__ short rawBin[CHUNK];        // 3.2 KB
        const int tid = threadIdx.x;
        for (int k = tid; k < NBINS; k += 256) hist[k] = 0;
        __syncthreads();
        const int base = b * CHUNK;

        // pass 1: single edge read, record build, LDS histogram
        for (int i = 0; i < CHUNK; i += 256) {
            const int j = i + tid;
            if (j >= CHUNK) continue;                 // chunk guard (CHUNK % 256 != 0)
            const int e = base + j;
            short binS = -1;
            if (e < N_EDGES) {
                const int di = ei[e];
                const int sj = ej[e];
                if (di != sj) {                       // centerIgnore
                    const float2 ea = ((const float2*)edge_attr)[e];
                    float ux = fminf(fmaxf(ea.x, -1.f), 1.f);
                    float uy = fminf(fmaxf(ea.y, -1.f), 1.f);
                    float tx = (ux + 1.f) * 1.5f;
                    float ty = (uy + 1.f) * 1.5f;
                    int kx0 = min((int)tx, 2);
                    int ky0 = min((int)ty, 2);
                    float fx = tx - (float)kx0;
                    float fy = ty - (float)ky0;
                    unsigned fx12 = (unsigned)(fx * 4095.f + 0.5f);
                    unsigned fy12 = (unsigned)(fy * 4095.f + 0.5f);
                    const int bin = di / NPB;
                    const unsigned local = (unsigned)(di - bin * NPB);   // < 196
                    rawA[j] = (unsigned)(sj * 512 + (kx0 * 4 + ky0) * 32);
                    rawB[j] = fx12 | (fy12 << 12) | (local << 24);
                    binS = (short)bin;
                    atomicAdd(&hist[bin], 1);
                }
            }
            rawBin[j] = binS;
        }
        __syncthreads();

        // pass 2: one returning global atomic per non-empty (block,bin)
        for (int k = tid; k < NBINS; k += 256) {
            const int c = hist[k];
            int g = 0;
            if (c > 0) g = atomicAdd(&cursor[k], c);
            hist[k] = k * CAPB + g;
        }
        __syncthreads();

        // pass 3: replay from LDS, slot via LDS atomic, store 8B record
        for (int i = 0; i < CHUNK; i += 256) {
            const int j = i + tid;
            if (j >= CHUNK) continue;
            const int bin = rawBin[j];
            if (bin < 0) continue;
            const int s = atomicAdd(&hist[bin], 1);
            if (s - bin * CAPB < CAPB) {
                bkt[s] = make_uint2(rawA[j], rawB[j]);
            } else {
                const int o = atomicAdd(ovfCnt, 1);
                if (o < OVF_CAP) ovf[o] = base + j;
            }
        }
    } else {
        const int bb = b - GA;
        const int kbase = (bb / NBY) * 4;
        const int n = (bb % NBY) * 256 + threadIdx.x;
        if (n >= N_NODES) return;

        const float4* xv = (const float4*)(x + n * 16);
        float4 a = xv[0], b2 = xv[1], c = xv[2], d = xv[3];
        float xr[16] = {a.x,a.y,a.z,a.w, b2.x,b2.y,b2.z,b2.w,
                        c.x,c.y,c.z,c.w, d.x,d.y,d.z,d.w};

        float acc[4][16];
#pragma unroll
        for (int kk = 0; kk < 4; ++kk)
#pragma unroll
            for (int o = 0; o < 16; ++o) acc[kk][o] = 0.f;

#pragma unroll
        for (int i = 0; i < 16; ++i) {
#pragma unroll
            for (int kk = 0; kk < 4; ++kk) {
                const float* wrow = W + ((kbase + kk) * 256 + i * 16);
#pragma unroll
                for (int o = 0; o < 16; ++o)
                    acc[kk][o] = fmaf(xr[i], wrow[o], acc[kk][o]);
            }
        }

        unsigned short* dst = Y + (size_t)n * 256 + kbase * 16;
#pragma unroll
        for (int kk = 0; kk < 4; ++kk) {
            unsigned pk[8];
#pragma unroll
            for (int q = 0; q < 8; ++q)
                pk[q] = (unsigned)f2bf(acc[kk][2*q]) | ((unsigned)f2bf(acc[kk][2*q+1]) << 16);
            uint4* p = (uint4*)(dst + kk * 16);
            p[0] = make_uint4(pk[0], pk[1], pk[2], pk[3]);
            p[1] = make_uint4(pk[4], pk[5], pk[6], pk[7]);
        }
    }
}

// ---- gather: one block per bin; records loaded to LDS once; counting-sort;
//      4 threads/node register accumulation; coalesced block store ----
__global__ __launch_bounds__(GB_T) void gather_sort(
    const int* __restrict__ cursor, const uint2* __restrict__ bkt,
    const unsigned short* __restrict__ Y, float* __restrict__ out) {
    const int bin = blockIdx.x;
    const int tid = threadIdx.x;
    __shared__ uint2 rawg[CAPB];          // 16 KB (single global read of records)
    __shared__ uint2 sorted[CAPB];        // 16 KB
    __shared__ int h[NPB];                // counts -> inclusive scan
    __shared__ int st[NPB], en[NPB], cur[NPB];
    __shared__ float tile[NPB * 16];      // 12.5 KB

    for (int j = tid; j < NPB; j += GB_T) h[j] = 0;
    __syncthreads();

    const int cnt = min(cursor[bin], CAPB);
    const uint2* rb = bkt + (size_t)bin * CAPB;

    // stage 0: bulk-load records to LDS (coalesced, ~2 iters)
    for (int p = tid; p < cnt; p += GB_T) rawg[p] = rb[p];
    __syncthreads();

    // stage 1: histogram over local nodes (from LDS)
    for (int p = tid; p < cnt; p += GB_T)
        atomicAdd(&h[rawg[p].y >> 24], 1);
    __syncthreads();

    // stage 2: Hillis-Steele inclusive scan of h[0..NPB)
    int c0 = (tid < NPB) ? h[tid] : 0;
    for (int off = 1; off < NPB; off <<= 1) {
        int tmp = 0;
        if (tid < NPB && tid >= off) tmp = h[tid - off];
        __syncthreads();
        if (tid < NPB) h[tid] += tmp;
        __syncthreads();
    }
    if (tid < NPB) {
        en[tid]  = h[tid];
        st[tid]  = h[tid] - c0;
        cur[tid] = h[tid] - c0;
    }
    __syncthreads();

    // stage 3: scatter into sorted order (LDS -> LDS)
    for (int p = tid; p < cnt; p += GB_T) {
        uint2 r = rawg[p];
        int pos = atomicAdd(&cur[r.y >> 24], 1);
        sorted[pos] = r;
    }
    __syncthreads();

    // stage 4: 4 threads per node (784 active), register accumulation
    const char* Yb = (const char*)Y;
    const float U = 1.f / 4095.f;
    const float S = 1.f / 128.f;                 // OUTPUT_SCALING
    if (tid < 4 * NPB) {
        const int node = tid >> 2;
        const int q4 = tid & 3;
        float acc[16];
#pragma unroll
        for (int o = 0; o < 16; ++o) acc[o] = 0.f;

        const int lo = st[node], hi2 = en[node];
        for (int idx = lo + q4; idx < hi2; idx += 4) {
            const uint2 m = sorted[idx];
            const float fx = (float)(m.y & 0xFFFu) * U;
            const float fy = (float)((m.y >> 12) & 0xFFFu) * U;
            const float w00 = (1.f - fx) * (1.f - fy) * S;
            const float w01 = (1.f - fx) * fy * S;
            const float w10 = fx * (1.f - fy) * S;
            const float w11 = fx * fy * S;

            const uint4* pA = (const uint4*)(Yb + m.x);
            const uint4* pB = (const uint4*)(Yb + m.x + 128);
            uint4 a0 = pA[0], a1 = pA[1], a2 = pA[2], a3 = pA[3];
            uint4 b0 = pB[0], b1 = pB[1], b2 = pB[2], b3 = pB[3];

            unsigned ra0[8] = {a0.x,a0.y,a0.z,a0.w, a1.x,a1.y,a1.z,a1.w};
            unsigned ra1[8] = {a2.x,a2.y,a2.z,a2.w, a3.x,a3.y,a3.z,a3.w};
            unsigned rb0[8] = {b0.x,b0.y,b0.z,b0.w, b1.x,b1.y,b1.z,b1.w};
            unsigned rb1[8] = {b2.x,b2.y,b2.z,b2.w, b3.x,b3.y,b3.z,b3.w};

#pragma unroll
            for (int q = 0; q < 8; ++q) {
                acc[2*q]   += bflo(ra0[q]) * w00 + bflo(ra1[q]) * w01
                            + bflo(rb0[q]) * w10 + bflo(rb1[q]) * w11;
                acc[2*q+1] += bfhi(ra0[q]) * w00 + bfhi(ra1[q]) * w01
                            + bfhi(rb0[q]) * w10 + bfhi(rb1[q]) * w11;
            }
        }
        // reduce across the 4-lane group (groups are lane-aligned, all active)
#pragma unroll
        for (int o = 0; o < 16; ++o) {
            acc[o] += __shfl_xor(acc[o], 1);
            acc[o] += __shfl_xor(acc[o], 2);
        }
        if (q4 == 0) {
            float* tr = &tile[node * 16];
#pragma unroll
            for (int o = 0; o < 16; ++o) tr[o] = acc[o];
        }
    }
    __syncthreads();

    // stage 5: coalesced block store (bins own disjoint node ranges)
    const int base = bin * NPB * 16;
    const int lim = N_NODES * 16 - base;
    for (int j = tid; j < NPB * 16; j += GB_T)
        if (j < lim) out[base + j] = tile[j];
}

// overflow fix-up: direct-compute rare capacity-overflow edges, atomic add.
__global__ __launch_bounds__(256) void overflow_kernel(
    const int* __restrict__ ovfCnt, const int* __restrict__ ovf,
    const float* __restrict__ x, const float* __restrict__ edge_attr,
    const float* __restrict__ W, const int* __restrict__ ei,
    const int* __restrict__ ej, float* __restrict__ out) {
    const int m = min(*ovfCnt, OVF_CAP);
    for (int i = blockIdx.x * 256 + threadIdx.x; i < m; i += gridDim.x * 256) {
        const int e = ovf[i];
        const int di = ei[e];
        const int sj = ej[e];
        const float2 ea = ((const float2*)edge_attr)[e];
        float ux = fminf(fmaxf(ea.x, -1.f), 1.f);
        float uy = fminf(fmaxf(ea.y, -1.f), 1.f);
        float tx = (ux + 1.f) * 1.5f, ty = (uy + 1.f) * 1.5f;
        int kx0 = min((int)tx, 2), ky0 = min((int)ty, 2);
        float fx = tx - (float)kx0, fy = ty - (float)ky0;
        const float S = 1.f / 128.f;
        float wgt[4] = {(1.f-fx)*(1.f-fy)*S, (1.f-fx)*fy*S, fx*(1.f-fy)*S, fx*fy*S};
        int kidx[4] = {kx0*4+ky0, kx0*4+ky0+1, (kx0+1)*4+ky0, (kx0+1)*4+ky0+1};

        const float* xj = x + (size_t)sj * 16;
        float msg[16];
#pragma unroll
        for (int o = 0; o < 16; ++o) msg[o] = 0.f;
#pragma unroll
        for (int p = 0; p < 4; ++p) {
            const float* wk = W + kidx[p] * 256;
            for (int ii = 0; ii < 16; ++ii) {
                float xw = xj[ii] * wgt[p];
#pragma unroll
                for (int o = 0; o < 16; ++o)
                    msg[o] = fmaf(xw, wk[ii * 16 + o], msg[o]);
            }
        }
        float* o16 = out + (size_t)di * 16;
#pragma unroll
        for (int o = 0; o < 16; ++o) atomicAdd(o16 + o, msg[o]);
    }
}

// ================= fallbacks =================
__global__ __launch_bounds__(256) void y_only_kernel(
    const float* __restrict__ x, const float* __restrict__ W,
    unsigned short* __restrict__ Y) {
    const int n = blockIdx.x * 256 + threadIdx.x;
    const int kbase = blockIdx.y * 4;
    if (n >= N_NODES) return;
    const float4* xv = (const float4*)(x + n * 16);
    float4 a = xv[0], b = xv[1], c = xv[2], d = xv[3];
    float xr[16] = {a.x,a.y,a.z,a.w, b.x,b.y,b.z,b.w,
                    c.x,c.y,c.z,c.w, d.x,d.y,d.z,d.w};
    float acc[4][16];
#pragma unroll
    for (int kk = 0; kk < 4; ++kk)
#pragma unroll
        for (int o = 0; o < 16; ++o) acc[kk][o] = 0.f;
#pragma unroll
    for (int i = 0; i < 16; ++i)
#pragma unroll
        for (int kk = 0; kk < 4; ++kk) {
            const float* wrow = W + ((kbase + kk) * 256 + i * 16);
#pragma unroll
            for (int o = 0; o < 16; ++o)
                acc[kk][o] = fmaf(xr[i], wrow[o], acc[kk][o]);
        }
    unsigned short* dst = Y + (size_t)n * 256 + kbase * 16;
#pragma unroll
    for (int kk = 0; kk < 4; ++kk) {
        unsigned pk[8];
#pragma unroll
        for (int q = 0; q < 8; ++q)
            pk[q] = (unsigned)f2bf(acc[kk][2*q]) | ((unsigned)f2bf(acc[kk][2*q+1]) << 16);
        uint4* p = (uint4*)(dst + kk * 16);
        p[0] = make_uint4(pk[0], pk[1], pk[2], pk[3]);
        p[1] = make_uint4(pk[4], pk[5], pk[6], pk[7]);
    }
}

__global__ __launch_bounds__(256) void edge_kernel(
    const float* __restrict__ edge_attr, const int* __restrict__ ei,
    const int* __restrict__ ej, const unsigned short* __restrict__ Y,
    float* __restrict__ out) {
    const int e = blockIdx.x * 256 + threadIdx.x;
    if (e >= N_EDGES) return;
    const int di = ei[e];
    const int sj = ej[e];
    const float2 ea = ((const float2*)edge_attr)[e];
    if (di == sj) return;
    float ux = fminf(fmaxf(ea.x, -1.f), 1.f);
    float uy = fminf(fmaxf(ea.y, -1.f), 1.f);
    float tx = (ux + 1.f) * 1.5f;
    float ty = (uy + 1.f) * 1.5f;
    int kx0 = min((int)tx, 2);
    int ky0 = min((int)ty, 2);
    float fx = tx - (float)kx0;
    float fy = ty - (float)ky0;
    const float S = 1.f / 128.f;
    float w00 = (1.f - fx) * (1.f - fy) * S;
    float w01 = (1.f - fx) * fy * S;
    float w10 = fx * (1.f - fy) * S;
    float w11 = fx * fy * S;
    const unsigned short* base = Y + (size_t)sj * 256 + (kx0 * 4 + ky0) * 16;
    const uint4* pA = (const uint4*)base;
    const uint4* pB = (const uint4*)(base + 64);
    uint4 a0 = pA[0], a1 = pA[1], a2 = pA[2], a3 = pA[3];
    uint4 b0 = pB[0], b1 = pB[1], b2 = pB[2], b3 = pB[3];
    unsigned ra0[8] = {a0.x,a0.y,a0.z,a0.w, a1.x,a1.y,a1.z,a1.w};
    unsigned ra1[8] = {a2.x,a2.y,a2.z,a2.w, a3.x,a3.y,a3.z,a3.w};
    unsigned rb0[8] = {b0.x,b0.y,b0.z,b0.w, b1.x,b1.y,b1.z,b1.w};
    unsigned rb1[8] = {b2.x,b2.y,b2.z,b2.w, b3.x,b3.y,b3.z,b3.w};
    float* o16 = out + (size_t)di * 16;
#pragma unroll
    for (int q = 0; q < 8; ++q) {
        float m0 = bflo(ra0[q]) * w00 + bflo(ra1[q]) * w01
                 + bflo(rb0[q]) * w10 + bflo(rb1[q]) * w11;
        float m1 = bfhi(ra0[q]) * w00 + bfhi(ra1[q]) * w01
                 + bfhi(rb0[q]) * w10 + bfhi(rb1[q]) * w11;
        atomicAdd(o16 + 2 * q, m0);
        atomicAdd(o16 + 2 * q + 1, m1);
    }
}

__global__ __launch_bounds__(256) void edge_direct(
    const float* __restrict__ x, const float* __restrict__ edge_attr,
    const float* __restrict__ W, const int* __restrict__ ei,
    const int* __restrict__ ej, float* __restrict__ out) {
    const int e = blockIdx.x * 256 + threadIdx.x;
    if (e >= N_EDGES) return;
    const int di = ei[e];
    const int sj = ej[e];
    const float2 ea = ((const float2*)edge_attr)[e];
    if (di == sj) return;
    float ux = fminf(fmaxf(ea.x, -1.f), 1.f);
    float uy = fminf(fmaxf(ea.y, -1.f), 1.f);
    float tx = (ux + 1.f) * 1.5f, ty = (uy + 1.f) * 1.5f;
    int kx0 = min((int)tx, 2), ky0 = min((int)ty, 2);
    float fx = tx - (float)kx0, fy = ty - (float)ky0;
    const float S = 1.f / 128.f;
    float wgt[4] = {(1.f-fx)*(1.f-fy)*S, (1.f-fx)*fy*S, fx*(1.f-fy)*S, fx*fy*S};
    int kidx[4] = {kx0*4+ky0, kx0*4+ky0+1, (kx0+1)*4+ky0, (kx0+1)*4+ky0+1};
    const float* xj = x + (size_t)sj * 16;
    float xr[16];
#pragma unroll
    for (int i = 0; i < 16; ++i) xr[i] = xj[i];
    float msg[16];
#pragma unroll
    for (int o = 0; o < 16; ++o) msg[o] = 0.f;
#pragma unroll
    for (int p = 0; p < 4; ++p) {
        const float* wk = W + kidx[p] * 256;
#pragma unroll
        for (int i = 0; i < 16; ++i) {
            float xw = xr[i] * wgt[p];
#pragma unroll
            for (int o = 0; o < 16; ++o)
                msg[o] = fmaf(xw, wk[i * 16 + o], msg[o]);
        }
    }
    float* o16 = out + (size_t)di * 16;
#pragma unroll
    for (int o = 0; o < 16; ++o) atomicAdd(o16 + o, msg[o]);
}

extern "C" void kernel_launch(void* const* d_in, const int* in_sizes, int n_in,
                              void* d_out, int out_size, void* d_ws, size_t ws_size,
                              hipStream_t stream) {
    const float* x         = (const float*)d_in[0];
    const float* edge_attr = (const float*)d_in[1];
    const float* W         = (const float*)d_in[2];
    const int*   ei        = (const int*)d_in[3];
    const int*   ej        = (const int*)d_in[4];
    float* out = (float*)d_out;
    char* ws = (char*)d_ws;

    // ---- bin-path workspace layout (16B aligned) ----
    const size_t oY      = 0;                                // 51,200,000
    const size_t oCur    = oY + (size_t)N_NODES * 512;       // 2,048
    const size_t oOvfCnt = oCur + (size_t)NBINS * 4;         // 16
    const size_t oOvf    = oOvfCnt + 16;                     // 262,144
    const size_t oBkt    = oOvf + (size_t)OVF_CAP * 4;       // NBINS*CAPB*8 = 8,388,608
    const size_t total   = oBkt + (size_t)NBINS * CAPB * 8;  // ~60 MB

    if (ws_size >= total) {
        unsigned short* Y = (unsigned short*)(ws + oY);
        int*   cursor = (int*)(ws + oCur);
        int*   ovfCnt = (int*)(ws + oOvfCnt);
        int*   ovf    = (int*)(ws + oOvf);
        uint2* bkt    = (uint2*)(ws + oBkt);

        hipMemsetAsync(cursor, 0, (size_t)NBINS * 4 + 16, stream);  // cursors + ovfCnt
        fused_bucket_y<<<GA + YBLK, 256, 0, stream>>>(
            x, W, Y, edge_attr, ei, ej, cursor, bkt, ovfCnt, ovf);
        gather_sort<<<NBINS, GB_T, 0, stream>>>(cursor, bkt, Y, out);
        overflow_kernel<<<32, 256, 0, stream>>>(ovfCnt, ovf, x, edge_attr, W, ei, ej, out);
        return;
    }

    const size_t yBytes = (size_t)N_NODES * 512;
    if (ws_size >= yBytes) {
        hipMemsetAsync(d_out, 0, (size_t)out_size * sizeof(float), stream);
        unsigned short* Y = (unsigned short*)d_ws;
        dim3 gA(NBY, 4);
        y_only_kernel<<<gA, 256, 0, stream>>>(x, W, Y);
        edge_kernel<<<HBLK, 256, 0, stream>>>(edge_attr, ei, ej, Y, out);
    } else {
        hipMemsetAsync(d_out, 0, (size_t)out_size * sizeof(float), stream);
        edge_direct<<<HBLK, 256, 0, stream>>>(x, edge_attr, W, ei, ej, out);
    }
}

// Round 13
// 148.466 us; speedup vs baseline: 1.0271x; 1.0190x over previous
//
#include <hip/hip_runtime.h>

#define N_NODES 100000
#define N_EDGES 800000
#define NBY    ((N_NODES + 255) / 256)             // 391
#define YBLK   (NBY * 4)                           // 1564 y-blocks
#define HBLK   ((N_EDGES + 255) / 256)             // 3125
#define OVF_CAP 65536
#define GA     500                                 // phase-A bucket blocks
#define CHUNK  1600                                // edges per phase-A block (500*1600 = 800000)
                                                   // CHUNK % 256 != 0 -> chunk loops need j<CHUNK guard
#define NBINS  512
#define NPB    196                                 // nodes per bin (512*196 = 100352)
#define CAPB   2048                                // slots/bin (mean 1562, sigma ~40)
#define GB_T   1024                                // gather block threads
// Y layout: [n][kx][ky][o] bf16 (ushort), plane = 256 ushort = 512 B per node

__device__ __forceinline__ unsigned short f2bf(float f) {
    union { float f; unsigned u; } v; v.f = f;
    unsigned u = v.u;
    return (unsigned short)((u + 0x7FFFu + ((u >> 16) & 1u)) >> 16);  // RNE
}
__device__ __forceinline__ float bflo(unsigned u) {
    union { unsigned u; float f; } v; v.u = u << 16; return v.f;
}
__device__ __forceinline__ float bfhi(unsigned u) {
    union { unsigned u; float f; } v; v.u = u & 0xFFFF0000u; return v.f;
}

// ---- fused: phase-A bucket build [0,GA) | y-transform [GA, GA+YBLK) ----
// Edge blocks: pass 1 reads edges ONCE, computes records into LDS + histogram;
// pass 2 allocates global runs (one returning atomic per (block,bin));
// pass 3 replays from LDS: slot via LDS atomic, 8B global store.
__global__ __launch_bounds__(256) void fused_bucket_y(
    const float* __restrict__ x, const float* __restrict__ W,
    unsigned short* __restrict__ Y, const float* __restrict__ edge_attr,
    const int* __restrict__ ei, const int* __restrict__ ej,
    int* __restrict__ cursor, uint2* __restrict__ bkt,
    int* __restrict__ ovfCnt, int* __restrict__ ovf) {
    const int b = blockIdx.x;
    if (b < GA) {
        __shared__ int hist[NBINS];            // 2 KB
        __shared__ unsigned rawA[CHUNK];       // 6.4 KB
        __shared__ unsigned rawB[CHUNK];       // 6.4 KB
        __shared__ short rawBin[CHUNK];        // 3.2 KB
        const int tid = threadIdx.x;
        for (int k = tid; k < NBINS; k += 256) hist[k] = 0;
        __syncthreads();
        const int base = b * CHUNK;

        // pass 1: single edge read, record build, LDS histogram
        for (int i = 0; i < CHUNK; i += 256) {
            const int j = i + tid;
            if (j >= CHUNK) continue;                 // chunk guard (CHUNK % 256 != 0)
            const int e = base + j;
            short binS = -1;
            if (e < N_EDGES) {
                const int di = ei[e];
                const int sj = ej[e];
                if (di != sj) {                       // centerIgnore
                    const float2 ea = ((const float2*)edge_attr)[e];
                    float ux = fminf(fmaxf(ea.x, -1.f), 1.f);
                    float uy = fminf(fmaxf(ea.y, -1.f), 1.f);
                    float tx = (ux + 1.f) * 1.5f;
                    float ty = (uy + 1.f) * 1.5f;
                    int kx0 = min((int)tx, 2);
                    int ky0 = min((int)ty, 2);
                    float fx = tx - (float)kx0;
                    float fy = ty - (float)ky0;
                    unsigned fx12 = (unsigned)(fx * 4095.f + 0.5f);
                    unsigned fy12 = (unsigned)(fy * 4095.f + 0.5f);
                    const int bin = di / NPB;
                    const unsigned local = (unsigned)(di - bin * NPB);   // < 196
                    rawA[j] = (unsigned)(sj * 512 + (kx0 * 4 + ky0) * 32);
                    rawB[j] = fx12 | (fy12 << 12) | (local << 24);
                    binS = (short)bin;
                    atomicAdd(&hist[bin], 1);
                }
            }
            rawBin[j] = binS;
        }
        __syncthreads();

        // pass 2: one returning global atomic per non-empty (block,bin)
        for (int k = tid; k < NBINS; k += 256) {
            const int c = hist[k];
            int g = 0;
            if (c > 0) g = atomicAdd(&cursor[k], c);
            hist[k] = k * CAPB + g;
        }
        __syncthreads();

        // pass 3: replay from LDS, slot via LDS atomic, store 8B record
        for (int i = 0; i < CHUNK; i += 256) {
            const int j = i + tid;
            if (j >= CHUNK) continue;
            const int bin = rawBin[j];
            if (bin < 0) continue;
            const int s = atomicAdd(&hist[bin], 1);
            if (s - bin * CAPB < CAPB) {
                bkt[s] = make_uint2(rawA[j], rawB[j]);
            } else {
                const int o = atomicAdd(ovfCnt, 1);
                if (o < OVF_CAP) ovf[o] = base + j;
            }
        }
    } else {
        const int bb = b - GA;
        const int kbase = (bb / NBY) * 4;
        const int n = (bb % NBY) * 256 + threadIdx.x;
        if (n >= N_NODES) return;

        const float4* xv = (const float4*)(x + n * 16);
        float4 a = xv[0], b2 = xv[1], c = xv[2], d = xv[3];
        float xr[16] = {a.x,a.y,a.z,a.w, b2.x,b2.y,b2.z,b2.w,
                        c.x,c.y,c.z,c.w, d.x,d.y,d.z,d.w};

        float acc[4][16];
#pragma unroll
        for (int kk = 0; kk < 4; ++kk)
#pragma unroll
            for (int o = 0; o < 16; ++o) acc[kk][o] = 0.f;

#pragma unroll
        for (int i = 0; i < 16; ++i) {
#pragma unroll
            for (int kk = 0; kk < 4; ++kk) {
                const float* wrow = W + ((kbase + kk) * 256 + i * 16);
#pragma unroll
                for (int o = 0; o < 16; ++o)
                    acc[kk][o] = fmaf(xr[i], wrow[o], acc[kk][o]);
            }
        }

        unsigned short* dst = Y + (size_t)n * 256 + kbase * 16;
#pragma unroll
        for (int kk = 0; kk < 4; ++kk) {
            unsigned pk[8];
#pragma unroll
            for (int q = 0; q < 8; ++q)
                pk[q] = (unsigned)f2bf(acc[kk][2*q]) | ((unsigned)f2bf(acc[kk][2*q+1]) << 16);
            uint4* p = (uint4*)(dst + kk * 16);
            p[0] = make_uint4(pk[0], pk[1], pk[2], pk[3]);
            p[1] = make_uint4(pk[4], pk[5], pk[6], pk[7]);
        }
    }
}

// ---- gather: one block per bin; LDS counting-sort (global reads, R11 style);
//      4 threads/node register accumulation; fused overflow fix-up; block store ----
__global__ __launch_bounds__(GB_T) void gather_sort(
    const int* __restrict__ cursor, const uint2* __restrict__ bkt,
    const unsigned short* __restrict__ Y, float* __restrict__ out,
    const int* __restrict__ ovfCnt, const int* __restrict__ ovf,
    const float* __restrict__ x, const float* __restrict__ edge_attr,
    const float* __restrict__ W, const int* __restrict__ ei,
    const int* __restrict__ ej) {
    const int bin = blockIdx.x;
    const int tid = threadIdx.x;
    __shared__ uint2 sorted[CAPB];        // 16 KB
    __shared__ int h[NPB];                // counts -> inclusive scan
    __shared__ int st[NPB], en[NPB], cur[NPB];
    __shared__ float tile[NPB * 16];      // 12.5 KB

    for (int j = tid; j < NPB; j += GB_T) h[j] = 0;
    __syncthreads();

    const int cnt = min(cursor[bin], CAPB);
    const uint2* rb = bkt + (size_t)bin * CAPB;

    // stage 1: histogram over local nodes (global read #1, overlaps atomics)
    for (int p = tid; p < cnt; p += GB_T)
        atomicAdd(&h[rb[p].y >> 24], 1);
    __syncthreads();

    // stage 2: Hillis-Steele inclusive scan of h[0..NPB)
    int c0 = (tid < NPB) ? h[tid] : 0;
    for (int off = 1; off < NPB; off <<= 1) {
        int tmp = 0;
        if (tid < NPB && tid >= off) tmp = h[tid - off];
        __syncthreads();
        if (tid < NPB) h[tid] += tmp;
        __syncthreads();
    }
    if (tid < NPB) {
        en[tid]  = h[tid];
        st[tid]  = h[tid] - c0;
        cur[tid] = h[tid] - c0;
    }
    __syncthreads();

    // stage 3: scatter into sorted order (global read #2, L2-hot)
    for (int p = tid; p < cnt; p += GB_T) {
        uint2 r = rb[p];
        int pos = atomicAdd(&cur[r.y >> 24], 1);
        sorted[pos] = r;
    }
    __syncthreads();

    // stage 4: 4 threads per node (784 active), register accumulation
    const char* Yb = (const char*)Y;
    const float U = 1.f / 4095.f;
    const float S = 1.f / 128.f;                 // OUTPUT_SCALING
    if (tid < 4 * NPB) {
        const int node = tid >> 2;
        const int q4 = tid & 3;
        float acc[16];
#pragma unroll
        for (int o = 0; o < 16; ++o) acc[o] = 0.f;

        const int lo = st[node], hi2 = en[node];
        for (int idx = lo + q4; idx < hi2; idx += 4) {
            const uint2 m = sorted[idx];
            const float fx = (float)(m.y & 0xFFFu) * U;
            const float fy = (float)((m.y >> 12) & 0xFFFu) * U;
            const float w00 = (1.f - fx) * (1.f - fy) * S;
            const float w01 = (1.f - fx) * fy * S;
            const float w10 = fx * (1.f - fy) * S;
            const float w11 = fx * fy * S;

            const uint4* pA = (const uint4*)(Yb + m.x);
            const uint4* pB = (const uint4*)(Yb + m.x + 128);
            uint4 a0 = pA[0], a1 = pA[1], a2 = pA[2], a3 = pA[3];
            uint4 b0 = pB[0], b1 = pB[1], b2 = pB[2], b3 = pB[3];

            unsigned ra0[8] = {a0.x,a0.y,a0.z,a0.w, a1.x,a1.y,a1.z,a1.w};
            unsigned ra1[8] = {a2.x,a2.y,a2.z,a2.w, a3.x,a3.y,a3.z,a3.w};
            unsigned rb0[8] = {b0.x,b0.y,b0.z,b0.w, b1.x,b1.y,b1.z,b1.w};
            unsigned rb1[8] = {b2.x,b2.y,b2.z,b2.w, b3.x,b3.y,b3.z,b3.w};

#pragma unroll
            for (int q = 0; q < 8; ++q) {
                acc[2*q]   += bflo(ra0[q]) * w00 + bflo(ra1[q]) * w01
                            + bflo(rb0[q]) * w10 + bflo(rb1[q]) * w11;
                acc[2*q+1] += bfhi(ra0[q]) * w00 + bfhi(ra1[q]) * w01
                            + bfhi(rb0[q]) * w10 + bfhi(rb1[q]) * w11;
            }
        }
        // reduce across the 4-lane group (groups are lane-aligned, all active)
#pragma unroll
        for (int o = 0; o < 16; ++o) {
            acc[o] += __shfl_xor(acc[o], 1);
            acc[o] += __shfl_xor(acc[o], 2);
        }
        if (q4 == 0) {
            float* tr = &tile[node * 16];
#pragma unroll
            for (int o = 0; o < 16; ++o) tr[o] = acc[o];
        }
    }
    __syncthreads();

    // stage 4b: fused overflow fix-up (ovfCnt is ~always 0 -> one read, skip)
    const int m = min(*ovfCnt, OVF_CAP);
    if (m > 0) {
        const int nlo = bin * NPB;
        const int nhi = min(nlo + NPB, N_NODES);
        for (int i = tid; i < m; i += GB_T) {
            const int e = ovf[i];
            const int di = ei[e];
            if (di < nlo || di >= nhi) continue;      // not my bin
            const int sj = ej[e];
            const float2 ea = ((const float2*)edge_attr)[e];
            float ux = fminf(fmaxf(ea.x, -1.f), 1.f);
            float uy = fminf(fmaxf(ea.y, -1.f), 1.f);
            float tx = (ux + 1.f) * 1.5f, ty = (uy + 1.f) * 1.5f;
            int kx0 = min((int)tx, 2), ky0 = min((int)ty, 2);
            float fx = tx - (float)kx0, fy = ty - (float)ky0;
            float wgt[4] = {(1.f-fx)*(1.f-fy)*S, (1.f-fx)*fy*S, fx*(1.f-fy)*S, fx*fy*S};
            int kidx[4] = {kx0*4+ky0, kx0*4+ky0+1, (kx0+1)*4+ky0, (kx0+1)*4+ky0+1};
            const float* xj = x + (size_t)sj * 16;
            float msg[16];
#pragma unroll
            for (int o = 0; o < 16; ++o) msg[o] = 0.f;
#pragma unroll
            for (int p = 0; p < 4; ++p) {
                const float* wk = W + kidx[p] * 256;
                for (int ii = 0; ii < 16; ++ii) {
                    float xw = xj[ii] * wgt[p];
#pragma unroll
                    for (int o = 0; o < 16; ++o)
                        msg[o] = fmaf(xw, wk[ii * 16 + o], msg[o]);
                }
            }
            float* tr = &tile[(di - nlo) * 16];
#pragma unroll
            for (int o = 0; o < 16; ++o) atomicAdd(tr + o, msg[o]);
        }
        __syncthreads();
    }

    // stage 5: coalesced block store (bins own disjoint node ranges)
    const int base = bin * NPB * 16;
    const int lim = N_NODES * 16 - base;
    for (int j = tid; j < NPB * 16; j += GB_T)
        if (j < lim) out[base + j] = tile[j];
}

// ================= fallbacks =================
__global__ __launch_bounds__(256) void y_only_kernel(
    const float* __restrict__ x, const float* __restrict__ W,
    unsigned short* __restrict__ Y) {
    const int n = blockIdx.x * 256 + threadIdx.x;
    const int kbase = blockIdx.y * 4;
    if (n >= N_NODES) return;
    const float4* xv = (const float4*)(x + n * 16);
    float4 a = xv[0], b = xv[1], c = xv[2], d = xv[3];
    float xr[16] = {a.x,a.y,a.z,a.w, b.x,b.y,b.z,b.w,
                    c.x,c.y,c.z,c.w, d.x,d.y,d.z,d.w};
    float acc[4][16];
#pragma unroll
    for (int kk = 0; kk < 4; ++kk)
#pragma unroll
        for (int o = 0; o < 16; ++o) acc[kk][o] = 0.f;
#pragma unroll
    for (int i = 0; i < 16; ++i)
#pragma unroll
        for (int kk = 0; kk < 4; ++kk) {
            const float* wrow = W + ((kbase + kk) * 256 + i * 16);
#pragma unroll
            for (int o = 0; o < 16; ++o)
                acc[kk][o] = fmaf(xr[i], wrow[o], acc[kk][o]);
        }
    unsigned short* dst = Y + (size_t)n * 256 + kbase * 16;
#pragma unroll
    for (int kk = 0; kk < 4; ++kk) {
        unsigned pk[8];
#pragma unroll
        for (int q = 0; q < 8; ++q)
            pk[q] = (unsigned)f2bf(acc[kk][2*q]) | ((unsigned)f2bf(acc[kk][2*q+1]) << 16);
        uint4* p = (uint4*)(dst + kk * 16);
        p[0] = make_uint4(pk[0], pk[1], pk[2], pk[3]);
        p[1] = make_uint4(pk[4], pk[5], pk[6], pk[7]);
    }
}

__global__ __launch_bounds__(256) void edge_kernel(
    const float* __restrict__ edge_attr, const int* __restrict__ ei,
    const int* __restrict__ ej, const unsigned short* __restrict__ Y,
    float* __restrict__ out) {
    const int e = blockIdx.x * 256 + threadIdx.x;
    if (e >= N_EDGES) return;
    const int di = ei[e];
    const int sj = ej[e];
    const float2 ea = ((const float2*)edge_attr)[e];
    if (di == sj) return;
    float ux = fminf(fmaxf(ea.x, -1.f), 1.f);
    float uy = fminf(fmaxf(ea.y, -1.f), 1.f);
    float tx = (ux + 1.f) * 1.5f;
    float ty = (uy + 1.f) * 1.5f;
    int kx0 = min((int)tx, 2);
    int ky0 = min((int)ty, 2);
    float fx = tx - (float)kx0;
    float fy = ty - (float)ky0;
    const float S = 1.f / 128.f;
    float w00 = (1.f - fx) * (1.f - fy) * S;
    float w01 = (1.f - fx) * fy * S;
    float w10 = fx * (1.f - fy) * S;
    float w11 = fx * fy * S;
    const unsigned short* base = Y + (size_t)sj * 256 + (kx0 * 4 + ky0) * 16;
    const uint4* pA = (const uint4*)base;
    const uint4* pB = (const uint4*)(base + 64);
    uint4 a0 = pA[0], a1 = pA[1], a2 = pA[2], a3 = pA[3];
    uint4 b0 = pB[0], b1 = pB[1], b2 = pB[2], b3 = pB[3];
    unsigned ra0[8] = {a0.x,a0.y,a0.z,a0.w, a1.x,a1.y,a1.z,a1.w};
    unsigned ra1[8] = {a2.x,a2.y,a2.z,a2.w, a3.x,a3.y,a3.z,a3.w};
    unsigned rb0[8] = {b0.x,b0.y,b0.z,b0.w, b1.x,b1.y,b1.z,b1.w};
    unsigned rb1[8] = {b2.x,b2.y,b2.z,b2.w, b3.x,b3.y,b3.z,b3.w};
    float* o16 = out + (size_t)di * 16;
#pragma unroll
    for (int q = 0; q < 8; ++q) {
        float m0 = bflo(ra0[q]) * w00 + bflo(ra1[q]) * w01
                 + bflo(rb0[q]) * w10 + bflo(rb1[q]) * w11;
        float m1 = bfhi(ra0[q]) * w00 + bfhi(ra1[q]) * w01
                 + bfhi(rb0[q]) * w10 + bfhi(rb1[q]) * w11;
        atomicAdd(o16 + 2 * q, m0);
        atomicAdd(o16 + 2 * q + 1, m1);
    }
}

__global__ __launch_bounds__(256) void edge_direct(
    const float* __restrict__ x, const float* __restrict__ edge_attr,
    const float* __restrict__ W, const int* __restrict__ ei,
    const int* __restrict__ ej, float* __restrict__ out) {
    const int e = blockIdx.x * 256 + threadIdx.x;
    if (e >= N_EDGES) return;
    const int di = ei[e];
    const int sj = ej[e];
    const float2 ea = ((const float2*)edge_attr)[e];
    if (di == sj) return;
    float ux = fminf(fmaxf(ea.x, -1.f), 1.f);
    float uy = fminf(fmaxf(ea.y, -1.f), 1.f);
    float tx = (ux + 1.f) * 1.5f, ty = (uy + 1.f) * 1.5f;
    int kx0 = min((int)tx, 2), ky0 = min((int)ty, 2);
    float fx = tx - (float)kx0, fy = ty - (float)ky0;
    const float S = 1.f / 128.f;
    float wgt[4] = {(1.f-fx)*(1.f-fy)*S, (1.f-fx)*fy*S, fx*(1.f-fy)*S, fx*fy*S};
    int kidx[4] = {kx0*4+ky0, kx0*4+ky0+1, (kx0+1)*4+ky0, (kx0+1)*4+ky0+1};
    const float* xj = x + (size_t)sj * 16;
    float xr[16];
#pragma unroll
    for (int i = 0; i < 16; ++i) xr[i] = xj[i];
    float msg[16];
#pragma unroll
    for (int o = 0; o < 16; ++o) msg[o] = 0.f;
#pragma unroll
    for (int p = 0; p < 4; ++p) {
        const float* wk = W + kidx[p] * 256;
#pragma unroll
        for (int i = 0; i < 16; ++i) {
            float xw = xr[i] * wgt[p];
#pragma unroll
            for (int o = 0; o < 16; ++o)
                msg[o] = fmaf(xw, wk[i * 16 + o], msg[o]);
        }
    }
    float* o16 = out + (size_t)di * 16;
#pragma unroll
    for (int o = 0; o < 16; ++o) atomicAdd(o16 + o, msg[o]);
}

extern "C" void kernel_launch(void* const* d_in, const int* in_sizes, int n_in,
                              void* d_out, int out_size, void* d_ws, size_t ws_size,
                              hipStream_t stream) {
    const float* x         = (const float*)d_in[0];
    const float* edge_attr = (const float*)d_in[1];
    const float* W         = (const float*)d_in[2];
    const int*   ei        = (const int*)d_in[3];
    const int*   ej        = (const int*)d_in[4];
    float* out = (float*)d_out;
    char* ws = (char*)d_ws;

    // ---- bin-path workspace layout (16B aligned) ----
    const size_t oY      = 0;                                // 51,200,000
    const size_t oCur    = oY + (size_t)N_NODES * 512;       // 2,048
    const size_t oOvfCnt = oCur + (size_t)NBINS * 4;         // 16
    const size_t oOvf    = oOvfCnt + 16;                     // 262,144
    const size_t oBkt    = oOvf + (size_t)OVF_CAP * 4;       // NBINS*CAPB*8 = 8,388,608
    const size_t total   = oBkt + (size_t)NBINS * CAPB * 8;  // ~60 MB

    if (ws_size >= total) {
        unsigned short* Y = (unsigned short*)(ws + oY);
        int*   cursor = (int*)(ws + oCur);
        int*   ovfCnt = (int*)(ws + oOvfCnt);
        int*   ovf    = (int*)(ws + oOvf);
        uint2* bkt    = (uint2*)(ws + oBkt);

        hipMemsetAsync(cursor, 0, (size_t)NBINS * 4 + 16, stream);  // cursors + ovfCnt
        fused_bucket_y<<<GA + YBLK, 256, 0, stream>>>(
            x, W, Y, edge_attr, ei, ej, cursor, bkt, ovfCnt, ovf);
        gather_sort<<<NBINS, GB_T, 0, stream>>>(
            cursor, bkt, Y, out, ovfCnt, ovf, x, edge_attr, W, ei, ej);
        return;
    }

    const size_t yBytes = (size_t)N_NODES * 512;
    if (ws_size >= yBytes) {
        hipMemsetAsync(d_out, 0, (size_t)out_size * sizeof(float), stream);
        unsigned short* Y = (unsigned short*)d_ws;
        dim3 gA(NBY, 4);
        y_only_kernel<<<gA, 256, 0, stream>>>(x, W, Y);
        edge_kernel<<<HBLK, 256, 0, stream>>>(edge_attr, ei, ej, Y, out);
    } else {
        hipMemsetAsync(d_out, 0, (size_t)out_size * sizeof(float), stream);
        edge_direct<<<HBLK, 256, 0, stream>>>(x, edge_attr, W, ei, ej, out);
    }
}